// Round 17
// baseline (1339.722 us; speedup 1.0000x reference)
//
#include <hip/hip_runtime.h>

// ---------------------------------------------------------------------------
// BiSSM global block, MI355X — round 17: radix-4 levels via SEQUENTIAL phases.
//   u[t]    = xn[t]@Bm^T (dup to fwd+bwd halves)            k_lvl<0>
//   X_4k[t] = X_k[t] + sum_{s=1..3} X_k[t-/+s*k]@(A^{sk})^T k_lvl<3> x5
//             (k = 1,4,16,64,256)
//   Xsum[t] = X_f[t]+X_f[t-1024]@W + X_b[t]+X_b[t+1024]@W   k_lvl<2> (W=A^1024)
//   out     = x + alpha*0.5*(Xsum@Cm^T)*sigmoid(xn@gw^T+gb) k_fin (dual GEMM)
// k_lvl<3>: 3 sequential K-loop phases, each staging 1 A-tile + 1 B-tile
// (byte-identical proven round-10 inner loop, 24KB/buf, 48KB 2-buf ->
// occupancy preserved); cross-phase ping-pong staging; acc accumulates
// across 72 virtual steps; res added once in epilogue. This fixes round-9's
// radix-4 failure (concurrent 3-stream staging + per-fragment B reads).
// Powers: 15 (A^1..A^1024 incl. x3 entries) via pair-batched k_mul chain
// (round-9 verified), retiled 64x64/(12,12,z) for CU coverage.
// ---------------------------------------------------------------------------

typedef short  bfrag __attribute__((ext_vector_type(8)));   // 8 x bf16
typedef float  ffrag __attribute__((ext_vector_type(4)));   // mfma acc
typedef float  f4    __attribute__((ext_vector_type(4)));
typedef short  s4v   __attribute__((ext_vector_type(4)));   // 4 x bf16

#define DEV static __device__ __forceinline__
#define Hn 768
#define FLS 132   // k_fin bounce stride (128+4)
#define BLS 260   // k_lvl bounce stride (256+4)

DEV unsigned short f2bf(float f) {
  unsigned u = __float_as_uint(f);
  u += 0x7fffu + ((u >> 16) & 1u);            // round-to-nearest-even
  return (unsigned short)(u >> 16);
}
DEV float bf2f(unsigned short s) { return __uint_as_float(((unsigned)s) << 16); }

DEV ffrag mfma16(bfrag a, bfrag b, ffrag c) {
  return __builtin_amdgcn_mfma_f32_16x16x32_bf16(a, b, c, 0, 0, 0);
}

DEV void glds16(const unsigned short* g, unsigned short* l) {
  __builtin_amdgcn_global_load_lds(
      (const __attribute__((address_space(1))) unsigned int*)g,
      (__attribute__((address_space(3))) unsigned int*)l, 16, 0, 0);
}

union BF8 { bfrag v; unsigned short u[8]; };

// ---------------------------------------------------------------------------
// k_abuild: gridDim = (768, 4); task = blockIdx.y
__global__ __launch_bounds__(256) void k_abuild(
    const float* __restrict__ U, const float* __restrict__ V,
    const float* __restrict__ S, const float* __restrict__ Bm,
    const float* __restrict__ Cm, const float* __restrict__ gw,
    float* __restrict__ Af, float* __restrict__ AfT,
    unsigned short* __restrict__ Abf,
    unsigned short* __restrict__ Bmb, unsigned short* __restrict__ Cmb,
    unsigned short* __restrict__ gwb, unsigned short* __restrict__ zp) {
  int i = blockIdx.x;
  int task = blockIdx.y;
  if (task == 0) {
    float u0 = U[i*4+0], u1 = U[i*4+1], u2 = U[i*4+2], u3 = U[i*4+3];
    for (int j = threadIdx.x; j < Hn; j += 256) {
      float a = u0*V[j*4+0] + u1*V[j*4+1] + u2*V[j*4+2] + u3*V[j*4+3]
              + S[i*Hn+j] - S[j*Hn+i];
      if (i == j) a += -(float)(i+1) / 768.0f;
      Af[i*Hn+j]  = a;
      AfT[j*Hn+i] = a;
      Abf[i*Hn+j] = f2bf(a);
    }
    if (i == 0) for (int j = threadIdx.x; j < 1024; j += 256) zp[j] = 0;
  } else {
    const float* src = (task==1) ? Bm : (task==2) ? Cm : gw;
    unsigned short* dst = (task==1) ? Bmb : (task==2) ? Cmb : gwb;
    for (int j = threadIdx.x; j < Hn; j += 256) dst[i*Hn+j] = f2bf(src[i*Hn+j]);
  }
}

// ---------------------------------------------------------------------------
// k_rms: one wave per row (row = b*2048 + t); write xn in (t,b) order, bf16.
__global__ __launch_bounds__(256) void k_rms(
    const float* __restrict__ x, const float* __restrict__ scale,
    unsigned short* __restrict__ xn) {
  int row  = blockIdx.x * 4 + (threadIdx.x >> 6);
  int lane = threadIdx.x & 63;
  int b = row >> 11, t = row & 2047;
  const float* xr = x + (long)row * Hn;
  float v[12];
  float ss = 0.f;
#pragma unroll
  for (int j = 0; j < 12; ++j) { v[j] = xr[lane + j*64]; ss += v[j]*v[j]; }
#pragma unroll
  for (int off = 1; off < 64; off <<= 1) ss += __shfl_xor(ss, off);
  float inv = 1.0f / sqrtf(ss / 768.0f + 1e-8f);
  unsigned short* dst = xn + ((long)t * 8 + b) * Hn;
#pragma unroll
  for (int j = 0; j < 12; ++j) dst[lane + j*64] = f2bf(v[j] * inv * scale[lane + j*64]);
}

// ---------------------------------------------------------------------------
// k_mul: Z = X @ Y (hi/lo bf16, 3 passes). YT = Y^T row-major (f32).
// Writes f32 Z/ZT if non-null + bf16 always. 64x64 tile, 256 thr (4 waves
// 2x2), grid (12, 12, nz); blockIdx.z picks parameter set.
__global__ __launch_bounds__(256) void k_mul(
    const float* __restrict__ X0, const float* __restrict__ Y0T,
    float* __restrict__ Z0, float* __restrict__ Z0T, unsigned short* __restrict__ Zb0,
    const float* __restrict__ X1, const float* __restrict__ Y1T,
    float* __restrict__ Z1, float* __restrict__ Z1T, unsigned short* __restrict__ Zb1) {
  const float* X  = blockIdx.z ? X1 : X0;
  const float* YT = blockIdx.z ? Y1T : Y0T;
  float* Z  = blockIdx.z ? Z1 : Z0;
  float* ZT = blockIdx.z ? Z1T : Z0T;
  unsigned short* Zb = blockIdx.z ? Zb1 : Zb0;

  int tid = threadIdx.x, lane = tid & 63, w = tid >> 6;
  int mw = w >> 1, nw = w & 1, l15 = lane & 15, lhi = lane >> 4;
  int rb = blockIdx.x * 64, cb = blockIdx.y * 64;
  ffrag acc[2][2] = {};
  for (int kt = 0; kt < 24; ++kt) {
    int k0 = kt*32 + lhi*8;
    BF8 ah[2], al[2], bh[2], bl[2];
#pragma unroll
    for (int mt = 0; mt < 2; ++mt) {
      const f4* p = (const f4*)(X + (long)(rb + mw*32 + mt*16 + l15) * Hn + k0);
      f4 x0 = p[0], x1 = p[1];
#pragma unroll
      for (int j = 0; j < 8; ++j) {
        float f = (j < 4) ? x0[j] : x1[j-4];
        unsigned short h = f2bf(f);
        ah[mt].u[j] = h; al[mt].u[j] = f2bf(f - bf2f(h));
      }
    }
#pragma unroll
    for (int nt = 0; nt < 2; ++nt) {
      const f4* p = (const f4*)(YT + (long)(cb + nw*32 + nt*16 + l15) * Hn + k0);
      f4 x0 = p[0], x1 = p[1];
#pragma unroll
      for (int j = 0; j < 8; ++j) {
        float f = (j < 4) ? x0[j] : x1[j-4];
        unsigned short h = f2bf(f);
        bh[nt].u[j] = h; bl[nt].u[j] = f2bf(f - bf2f(h));
      }
    }
#pragma unroll
    for (int mt = 0; mt < 2; ++mt)
#pragma unroll
      for (int nt = 0; nt < 2; ++nt) {
        acc[mt][nt] = mfma16(ah[mt].v, bh[nt].v, acc[mt][nt]);
        acc[mt][nt] = mfma16(ah[mt].v, bl[nt].v, acc[mt][nt]);
        acc[mt][nt] = mfma16(al[mt].v, bh[nt].v, acc[mt][nt]);
      }
  }
#pragma unroll
  for (int mt = 0; mt < 2; ++mt)
#pragma unroll
    for (int nt = 0; nt < 2; ++nt)
#pragma unroll
      for (int q = 0; q < 4; ++q) {
        int grow = rb + mw*32 + mt*16 + lhi*4 + q;
        int gcol = cb + nw*32 + nt*16 + l15;
        float vv = acc[mt][nt][q];
        if (Z)  Z[(long)grow*Hn + gcol] = vv;
        if (ZT) ZT[(long)gcol*Hn + grow] = vv;
        Zb[(long)grow*Hn + gcol] = f2bf(vv);
      }
}

// ---------------------------------------------------------------------------
// k_lvl<MODE>: 128x256 block tile, BK=32, 512 thr (8 waves 2x4, wave 64x64).
// 2-buf LDS, stage-early, ONE __syncthreads per step.
// MODE 0 (u):      out = A0 @ B0^T, dup-write both halves.        grid 384
// MODE 2 (combine):out = res[r]+res[r+16384]
//                        + (A0[r-sh]+A0[r+16384+sh]) @ B0^T.      grid 384
// MODE 3 (radix4): out = res + sum_{s=0..2} A0[r -/+ (s+1)*sh] @ Bs^T,
//                  3 sequential phases, cross-phase ping-pong.    grid 768
template<int MODE>
__global__ __launch_bounds__(512) void k_lvl(
    const unsigned short* __restrict__ A0s, const unsigned short* __restrict__ B0s,
    const unsigned short* __restrict__ B1s, const unsigned short* __restrict__ B2s,
    const unsigned short* __restrict__ res, unsigned short* __restrict__ outb,
    const unsigned short* __restrict__ zp, int sh) {
  constexpr int NS   = (MODE == 2) ? 2 : 1;        // staged A streams/buffer
  constexpr int BUFS = NS * 4096 + 8192;           // shorts per buffer
  __shared__ __align__(16) unsigned short ldsb[2 * BUFS];

  const int tid = threadIdx.x, lane = tid & 63, w = tid >> 6;
  const int l15 = lane & 15, lhi = lane >> 4;
  const int wr = w >> 2, wc = w & 3;               // 2 x 4 wave grid

  // XCD-aware bijective block swizzle (m204), col-fast decompose (ncol=3).
  const int nwg = gridDim.x;
  const int q8 = nwg >> 3, r8 = nwg & 7, xcd = blockIdx.x & 7, fo = blockIdx.x >> 3;
  const int wg = (xcd < r8 ? xcd*(q8+1) : r8*(q8+1) + (xcd - r8)*q8) + fo;
  const int cb = wg % 3, rbk = wg / 3;
  const long r0  = (long)rbk * 128;
  const long bc0 = (long)cb * 256;
  const int dir = (MODE == 3 && r0 >= 16384) ? 1 : 0;

  bool skip = false;
  if (MODE == 3)
    skip = dir ? (r0 >= 32768 - sh) : (r0 + 128 <= sh);

  // staging: A tile 128x32 (8KB) = 1 glds16/thread; B tile 256x32 = 2.
  const int rowin = lane >> 2, ch = lane & 3;
  const int rA = w*16 + rowin;
  const int cswz = ch ^ ((rowin ^ (rowin >> 2)) & 3);  // row%16 = rowin
  long gA[NS]; bool vA[NS];
#pragma unroll
  for (int s = 0; s < NS; ++s) {
    long gr; bool ok = true;
    if (MODE == 0 || MODE == 3) {
      gr = r0 + rA;                        // (MODE 3 overrides below)
    } else {                               // MODE 2
      if (s == 0) { gr = r0 + rA - sh;         ok = (gr >= 0);    }
      else        { gr = r0 + rA + 16384 + sh; ok = (gr < 32768); }
    }
    vA[s] = ok; gA[s] = gr * Hn + cswz*8;
  }
  long gA3[3]; bool vA3[3];
  if (MODE == 3) {
#pragma unroll
    for (int s = 0; s < 3; ++s) {
      long gr = r0 + rA + (dir ? (long)(s+1)*sh : -(long)(s+1)*sh);
      vA3[s] = dir ? (gr < 32768) : (gr >= 0);
      gA3[s] = gr * Hn + cswz*8;
    }
  }
  long gB[2];
#pragma unroll
  for (int j = 0; j < 2; ++j)
    gB[j] = (bc0 + j*128 + rA) * Hn + cswz*8;

  auto stage = [&](int buf, int kt) {              // MODE 0 / 2
    const int ko = kt * 32;
    unsigned short* dst = ldsb + buf * BUFS;
#pragma unroll
    for (int s = 0; s < NS; ++s) {
      const unsigned short* g = vA[s] ? (A0s + gA[s] + ko) : zp;
      glds16(g, dst + s*4096 + w*512);
    }
#pragma unroll
    for (int j = 0; j < 2; ++j)
      glds16(B0s + gB[j] + ko, dst + NS*4096 + j*4096 + w*512);
  };

  auto stage3 = [&](int buf, int s, int kt) {      // MODE 3, s compile-time
    const int ko = kt * 32;
    unsigned short* dst = ldsb + buf * BUFS;
    const unsigned short* g = vA3[s] ? (A0s + gA3[s] + ko) : zp;
    glds16(g, dst + w*512);
    const unsigned short* Bs = (s == 0) ? B0s : (s == 1) ? B1s : B2s;
#pragma unroll
    for (int j = 0; j < 2; ++j)
      glds16(Bs + gB[j] + ko, dst + 4096 + j*4096 + w*512);
  };

  ffrag acc[4][4] = {};
  const int cx = (lhi ^ ((l15 ^ (l15 >> 2)) & 3)) * 8;   // swizzled read chunk

  if (MODE == 3) {
    if (!skip) {
      stage3(0, 0, 0);
      __syncthreads();
      int cur = 0;
#pragma unroll
      for (int s = 0; s < 3; ++s) {
        for (int kt = 0; kt < 24; ++kt) {
          if (kt < 23)      stage3(cur ^ 1, s, kt + 1);
          else if (s < 2)   stage3(cur ^ 1, s + 1, 0);
          const unsigned short* L = ldsb + cur * BUFS;
          bfrag a[4], b[4];
#pragma unroll
          for (int mt = 0; mt < 4; ++mt)
            a[mt] = *(const bfrag*)&L[(wr*64 + mt*16 + l15)*32 + cx];
#pragma unroll
          for (int nt = 0; nt < 4; ++nt)
            b[nt] = *(const bfrag*)&L[4096 + (wc*64 + nt*16 + l15)*32 + cx];
#pragma unroll
          for (int mt = 0; mt < 4; ++mt)
#pragma unroll
            for (int nt = 0; nt < 4; ++nt)
              acc[mt][nt] = mfma16(a[mt], b[nt], acc[mt][nt]);
          __syncthreads();
          cur ^= 1;
        }
      }
    }
  } else {
    stage(0, 0);
    __syncthreads();
    int cur = 0;
    for (int kt = 0; kt < 24; ++kt) {
      if (kt < 23) stage(cur ^ 1, kt + 1);
      const unsigned short* L = ldsb + cur * BUFS;
      bfrag a[NS][4], b[4];
#pragma unroll
      for (int mt = 0; mt < 4; ++mt) {
        const int row = wr*64 + mt*16 + l15;
#pragma unroll
        for (int s = 0; s < NS; ++s)
          a[s][mt] = *(const bfrag*)&L[s*4096 + row*32 + cx];
      }
#pragma unroll
      for (int nt = 0; nt < 4; ++nt) {
        const int row = wc*64 + nt*16 + l15;
        b[nt] = *(const bfrag*)&L[NS*4096 + row*32 + cx];
      }
#pragma unroll
      for (int mt = 0; mt < 4; ++mt)
#pragma unroll
        for (int nt = 0; nt < 4; ++nt) {
          acc[mt][nt] = mfma16(a[0][mt], b[nt], acc[mt][nt]);
          if (NS == 2) acc[mt][nt] = mfma16(a[1][mt], b[nt], acc[mt][nt]);
        }
      __syncthreads();
      cur ^= 1;
    }
  }

  // ---- epilogue: 4 phases; phase p bounces acc[p] (32 rows x 256 f32) ----
  float* fl = (float*)ldsb;                  // 32 x BLS f32 = 33280 B
#pragma unroll
  for (int p = 0; p < 4; ++p) {
    __syncthreads();
#pragma unroll
    for (int nt = 0; nt < 4; ++nt)
#pragma unroll
      for (int q = 0; q < 4; ++q)
        fl[(wr*16 + lhi*4 + q)*BLS + wc*64 + nt*16 + l15] = acc[p][nt][q];
    __syncthreads();
    for (int i = tid; i < 2048; i += 512) {
      const int srow = i >> 6;               // 0..31
      const int cc   = (i & 63) << 2;        // 0..252
      f4 v = *(const f4*)&fl[srow*BLS + cc];
      const long grow = r0 + (srow >> 4)*64 + p*16 + (srow & 15);
      const long gcol = bc0 + cc;
      const long go = grow * Hn + gcol;
      if (MODE == 0) {
        s4v ov;
#pragma unroll
        for (int j = 0; j < 4; ++j) ((unsigned short*)&ov)[j] = f2bf(v[j]);
        *(s4v*)&outb[go] = ov;
        *(s4v*)&outb[go + (long)16384*Hn] = ov;
      } else if (MODE == 3) {
        s4v rv = *(const s4v*)&res[go];
#pragma unroll
        for (int j = 0; j < 4; ++j) v[j] += bf2f(((unsigned short*)&rv)[j]);
        s4v ov;
#pragma unroll
        for (int j = 0; j < 4; ++j) ((unsigned short*)&ov)[j] = f2bf(v[j]);
        *(s4v*)&outb[go] = ov;
      } else {
        s4v ra = *(const s4v*)&res[go];
        s4v rb2 = *(const s4v*)&res[go + (long)16384*Hn];
#pragma unroll
        for (int j = 0; j < 4; ++j)
          v[j] += bf2f(((unsigned short*)&ra)[j]) + bf2f(((unsigned short*)&rb2)[j]);
        s4v ov;
#pragma unroll
        for (int j = 0; j < 4; ++j) ((unsigned short*)&ov)[j] = f2bf(v[j]);
        *(s4v*)&outb[go] = ov;
      }
    }
  }
}

// ---------------------------------------------------------------------------
// k_fin: fused final. 128x128 tile, BK=32, 256 thr (4 waves 2x2, wave 64x64).
// 2-buf, vmcnt(0)+barrier+stage(kt+1).
// outf = x + alpha*0.5*(A0@B0^T) * sigmoid(A1@B1^T + gb)   (row = t*8+b)
__global__ __launch_bounds__(256) void k_fin(
    const unsigned short* __restrict__ A0s, const unsigned short* __restrict__ A1s,
    const unsigned short* __restrict__ B0s, const unsigned short* __restrict__ B1s,
    const unsigned short* __restrict__ zp,
    const float* __restrict__ gb, const float* __restrict__ alpha,
    const float* __restrict__ x, float* __restrict__ outf) {
  __shared__ __align__(16) char smem[2 * 4 * 8192];
  unsigned short* ldsb = (unsigned short*)smem;

  const int tid = threadIdx.x, lane = tid & 63, w = tid >> 6;
  const int l15 = lane & 15, lhi = lane >> 4;
  const int wr = w >> 1, wc = w & 1;

  const int nwg = gridDim.x;
  const int q8 = nwg >> 3, r8 = nwg & 7, xcd = blockIdx.x & 7, fo = blockIdx.x >> 3;
  const int wg = (xcd < r8 ? xcd*(q8+1) : r8*(q8+1) + (xcd - r8)*q8) + fo;
  const int cb = wg % 6, rbk = wg / 6;
  const long r0 = (long)rbk * 128;
  const long bc0 = (long)cb * 128;

  const int rowin = lane >> 2, ch = lane & 3;
  long gA[2][2]; long gB[2][2]; int lbase[2];
#pragma unroll
  for (int jj = 0; jj < 2; ++jj) {
    const int inst = w*2 + jj;
    const int r = inst*16 + rowin;
    const int c = ch ^ ((r ^ (r >> 2)) & 3);
    lbase[jj] = inst * 512;
    gA[0][jj] = (r0 + r) * Hn + c*8;
    gA[1][jj] = gA[0][jj];
    gB[0][jj] = (bc0 + r) * Hn + c*8;
    gB[1][jj] = gB[0][jj];
  }

  auto stage = [&](int buf, int kt) {
    const int ko = kt * 32;
    unsigned short* dst = ldsb + buf * 16384;
#pragma unroll
    for (int jj = 0; jj < 2; ++jj) {
      glds16(A0s + gA[0][jj] + ko, dst + 0*4096 + lbase[jj]);
      glds16(A1s + gA[1][jj] + ko, dst + 1*4096 + lbase[jj]);
      glds16(B0s + gB[0][jj] + ko, dst + 2*4096 + lbase[jj]);
      glds16(B1s + gB[1][jj] + ko, dst + 3*4096 + lbase[jj]);
    }
  };

  ffrag acc[4][4] = {};
  ffrag accZ[4][4] = {};
  const int cx = (lhi ^ ((l15 ^ (l15 >> 2)) & 3)) * 8;

  stage(0, 0);
  int cur = 0;
  for (int kt = 0; kt < 24; ++kt) {
    asm volatile("s_waitcnt vmcnt(0)" ::: "memory");
    __builtin_amdgcn_s_barrier();
    if (kt < 23) stage(cur ^ 1, kt + 1);
    const unsigned short* L = ldsb + cur * 16384;
    bfrag a[2][4], b0[4], b1[4];
#pragma unroll
    for (int mt = 0; mt < 4; ++mt) {
      const int row = wr*64 + mt*16 + l15;
      a[0][mt] = *(const bfrag*)&L[row*32 + cx];
      a[1][mt] = *(const bfrag*)&L[4096 + row*32 + cx];
    }
#pragma unroll
    for (int nt = 0; nt < 4; ++nt) {
      const int row = wc*64 + nt*16 + l15;
      b0[nt] = *(const bfrag*)&L[2*4096 + row*32 + cx];
      b1[nt] = *(const bfrag*)&L[3*4096 + row*32 + cx];
    }
#pragma unroll
    for (int mt = 0; mt < 4; ++mt)
#pragma unroll
      for (int nt = 0; nt < 4; ++nt) {
        acc[mt][nt]  = mfma16(a[0][mt], b0[nt], acc[mt][nt]);
        accZ[mt][nt] = mfma16(a[1][mt], b1[nt], accZ[mt][nt]);
      }
    cur ^= 1;
  }

  // gate in fragment layout
  const float al = alpha[0];
  float gvals[4];
#pragma unroll
  for (int nt = 0; nt < 4; ++nt) gvals[nt] = gb[bc0 + wc*64 + nt*16 + l15];
#pragma unroll
  for (int mt = 0; mt < 4; ++mt)
#pragma unroll
    for (int nt = 0; nt < 4; ++nt)
#pragma unroll
      for (int q = 0; q < 4; ++q) {
        float z = accZ[mt][nt][q] + gvals[nt];
        float g = 1.0f / (1.0f + __expf(-z));
        acc[mt][nt][q] *= al * 0.5f * g;
      }

  float* fl = (float*)smem;                 // 64 x FLS f32
#pragma unroll
  for (int hh = 0; hh < 2; ++hh) {
    __syncthreads();
    if (wr == hh) {
#pragma unroll
      for (int mt = 0; mt < 4; ++mt)
#pragma unroll
        for (int nt = 0; nt < 4; ++nt)
#pragma unroll
          for (int q = 0; q < 4; ++q)
            fl[(mt*16 + lhi*4 + q)*FLS + wc*64 + nt*16 + l15] = acc[mt][nt][q];
    }
    __syncthreads();
    for (int i = tid; i < 2048; i += 256) {
      const int row = i >> 5;
      const int cc  = (i & 31) << 2;
      f4 v = *(const f4*)&fl[row*FLS + cc];
      const long grow = r0 + hh*64 + row;
      const long gcol = bc0 + cc;
      const long t = grow >> 3, b = grow & 7;
      const long o = (b*2048 + t)*Hn + gcol;
      f4 xv = *(const f4*)&x[o];
      f4 ov;
#pragma unroll
      for (int j = 0; j < 4; ++j) ov[j] = xv[j] + v[j];
      *(f4*)&outf[o] = ov;
    }
  }
}

// ---------------------------------------------------------------------------
extern "C" void kernel_launch(void* const* d_in, const int* in_sizes, int n_in,
                              void* d_out, int out_size, void* d_ws, size_t ws_size,
                              hipStream_t stream) {
  const float* x     = (const float*)d_in[0];
  const float* scale = (const float*)d_in[1];
  const float* U     = (const float*)d_in[2];
  const float* V     = (const float*)d_in[3];
  const float* S     = (const float*)d_in[4];
  const float* Bm    = (const float*)d_in[5];
  const float* Cm    = (const float*)d_in[6];
  const float* gw    = (const float*)d_in[7];
  const float* gb    = (const float*)d_in[8];
  const float* alpha = (const float*)d_in[9];
  float* out = (float*)d_out;

  char* p = (char*)d_ws;
  auto alloc = [&](size_t sz) { char* r = p; p += (sz + 255) & ~(size_t)255; return r; };

  const size_t SZ_X  = (size_t)32768 * Hn * sizeof(unsigned short);  // 50.3MB
  const size_t SZ_BF = (size_t)16384 * Hn * sizeof(unsigned short);  // 25.2MB
  const size_t SZ_M  = (size_t)Hn * Hn * sizeof(float);              // 2.36MB
  const size_t SZ_MB = (size_t)Hn * Hn * sizeof(unsigned short);     // 1.18MB

  unsigned short* xn = (unsigned short*)alloc(SZ_BF);
  unsigned short* XA = (unsigned short*)alloc(SZ_X);
  unsigned short* XB = (unsigned short*)alloc(SZ_X);
  float* Af  = (float*)alloc(SZ_M);
  float* AfT = (float*)alloc(SZ_M);
  float* K0  = (float*)alloc(SZ_M);  float* K0T = (float*)alloc(SZ_M);
  float* K1  = (float*)alloc(SZ_M);  float* K1T = (float*)alloc(SZ_M);
  float* K2  = (float*)alloc(SZ_M);  float* K2T = (float*)alloc(SZ_M);
  unsigned short* Abf = (unsigned short*)alloc(SZ_MB);
  unsigned short* Pb[15];  // A^2,3,4,8,12,16,32,48,64,128,192,256,512,768,1024
  for (int i = 0; i < 15; ++i) Pb[i] = (unsigned short*)alloc(SZ_MB);
  unsigned short* A2b=Pb[0],*A3b=Pb[1],*A4b=Pb[2],*A8b=Pb[3],*A12b=Pb[4],
      *A16b=Pb[5],*A32b=Pb[6],*A48b=Pb[7],*A64b=Pb[8],*A128b=Pb[9],
      *A192b=Pb[10],*A256b=Pb[11],*A512b=Pb[12],*A768b=Pb[13],*A1024b=Pb[14];
  unsigned short* Bmb = (unsigned short*)alloc(SZ_MB);
  unsigned short* Cmb = (unsigned short*)alloc(SZ_MB);
  unsigned short* gwb = (unsigned short*)alloc(SZ_MB);
  unsigned short* zp  = (unsigned short*)alloc(1024 * sizeof(unsigned short));

  if ((size_t)(p - (char*)d_ws) > ws_size) return;  // workspace too small

  k_abuild<<<dim3(768, 4), 256, 0, stream>>>(U, V, S, Bm, Cm, gw,
      Af, AfT, Abf, Bmb, Cmb, gwb, zp);
  k_rms<<<4096, 256, 0, stream>>>(x, scale, xn);

  // power chain (15 powers, 10 launches; 3 rotating f32 slots K0..K2)
  dim3 g1(12, 12, 1), g2(12, 12, 2);
  k_mul<<<g1, 256, 0, stream>>>(Af, AfT, K0, K0T, A2b,
                                nullptr, nullptr, nullptr, nullptr, nullptr);
  k_mul<<<g2, 256, 0, stream>>>(Af, K0T, nullptr, nullptr, A3b,
                                K0, K0T, K1, K1T, A4b);
  k_mul<<<g1, 256, 0, stream>>>(K1, K1T, K2, K2T, A8b,
                                nullptr, nullptr, nullptr, nullptr, nullptr);
  k_mul<<<g2, 256, 0, stream>>>(K1, K2T, nullptr, nullptr, A12b,
                                K2, K2T, K0, K0T, A16b);
  k_mul<<<g1, 256, 0, stream>>>(K0, K0T, K1, K1T, A32b,
                                nullptr, nullptr, nullptr, nullptr, nullptr);
  k_mul<<<g2, 256, 0, stream>>>(K0, K1T, nullptr, nullptr, A48b,
                                K1, K1T, K2, K2T, A64b);
  k_mul<<<g1, 256, 0, stream>>>(K2, K2T, K0, K0T, A128b,
                                nullptr, nullptr, nullptr, nullptr, nullptr);
  k_mul<<<g2, 256, 0, stream>>>(K2, K0T, nullptr, nullptr, A192b,
                                K0, K0T, K1, K1T, A256b);
  k_mul<<<g1, 256, 0, stream>>>(K1, K1T, K2, K2T, A512b,
                                nullptr, nullptr, nullptr, nullptr, nullptr);
  k_mul<<<g2, 256, 0, stream>>>(K1, K2T, nullptr, nullptr, A768b,
                                K2, K2T, nullptr, nullptr, A1024b);

  // u = xn@Bm^T, duplicated into fwd+bwd halves of XA   (X_1)
  k_lvl<0><<<384, 512, 0, stream>>>(xn, Bmb, nullptr, nullptr,
      nullptr, XA, zp, 0);

  // radix-4 levels: X_1 -> X_4 -> X_16 -> X_64 -> X_256 -> X_1024
  k_lvl<3><<<768, 512, 0, stream>>>(XA, Abf,   A2b,   A3b,   XA, XB, zp, 8);
  k_lvl<3><<<768, 512, 0, stream>>>(XB, A4b,   A8b,   A12b,  XB, XA, zp, 32);
  k_lvl<3><<<768, 512, 0, stream>>>(XA, A16b,  A32b,  A48b,  XA, XB, zp, 128);
  k_lvl<3><<<768, 512, 0, stream>>>(XB, A64b,  A128b, A192b, XB, XA, zp, 512);
  k_lvl<3><<<768, 512, 0, stream>>>(XA, A256b, A512b, A768b, XA, XB, zp, 2048);

  // combine (k=1024) + fwd/bwd sum -> XA rows [0,16384)
  k_lvl<2><<<384, 512, 0, stream>>>(XB, A1024b, nullptr, nullptr,
      XB, XA, zp, 8192);

  // out = x + alpha*0.5*(Xsum@Cm^T)*sigmoid(xn@gw^T+gb)
  k_fin<<<768, 256, 0, stream>>>(XA, xn, Cmb, gwb, zp, gb, alpha, x, out);
}

// Round 18
// 1228.136 us; speedup vs baseline: 1.0909x; 1.0909x over previous
//
#include <hip/hip_runtime.h>

// ---------------------------------------------------------------------------
// BiSSM global block, MI355X — round 18: terminal config = round-16 measured
// best (1226us). 10 radix-2 doubling levels (proven 128x256/8-wave/2-buf),
// combine, dual-GEMM fused final, parallel-retiled k_sq chain.
//   u[t]    = xn[t]@Bm^T (dup to fwd+bwd halves)            k_lvl<0>
//   X_2k[t] = X_k[t] + X_k[t-/+k]@(A^k)^T, k=1..512          k_lvl<1> x10
//   Xsum[t] = X_f[t]+X_f[t-1024]@W + X_b[t]+X_b[t+1024]@W    k_lvl<2> (W=A^1024)
//   out     = x + alpha*0.5*(Xsum@Cm^T)*sigmoid(xn@gw^T+gb)  k_fin (dual GEMM)
// Session evidence: per-pass cost flat (74-78us) across 8 schedule variants;
// fusion loses to occupancy; radix-4 loses to traffic. This is the floor for
// the log-doubling decomposition at HIP-source scheduling.
// ---------------------------------------------------------------------------

typedef short  bfrag __attribute__((ext_vector_type(8)));   // 8 x bf16
typedef float  ffrag __attribute__((ext_vector_type(4)));   // mfma acc
typedef float  f4    __attribute__((ext_vector_type(4)));
typedef short  s4v   __attribute__((ext_vector_type(4)));   // 4 x bf16

#define DEV static __device__ __forceinline__
#define Hn 768
#define FLS 132   // k_fin bounce stride (128+4)
#define BLS 260   // k_lvl bounce stride (256+4)

DEV unsigned short f2bf(float f) {
  unsigned u = __float_as_uint(f);
  u += 0x7fffu + ((u >> 16) & 1u);            // round-to-nearest-even
  return (unsigned short)(u >> 16);
}
DEV float bf2f(unsigned short s) { return __uint_as_float(((unsigned)s) << 16); }

DEV ffrag mfma16(bfrag a, bfrag b, ffrag c) {
  return __builtin_amdgcn_mfma_f32_16x16x32_bf16(a, b, c, 0, 0, 0);
}

DEV void glds16(const unsigned short* g, unsigned short* l) {
  __builtin_amdgcn_global_load_lds(
      (const __attribute__((address_space(1))) unsigned int*)g,
      (__attribute__((address_space(3))) unsigned int*)l, 16, 0, 0);
}

union BF8 { bfrag v; unsigned short u[8]; };

// ---------------------------------------------------------------------------
// k_abuild: gridDim = (768, 4); task = blockIdx.y
__global__ __launch_bounds__(256) void k_abuild(
    const float* __restrict__ U, const float* __restrict__ V,
    const float* __restrict__ S, const float* __restrict__ Bm,
    const float* __restrict__ Cm, const float* __restrict__ gw,
    float* __restrict__ Af, float* __restrict__ AfT,
    unsigned short* __restrict__ Abf,
    unsigned short* __restrict__ Bmb, unsigned short* __restrict__ Cmb,
    unsigned short* __restrict__ gwb, unsigned short* __restrict__ zp) {
  int i = blockIdx.x;
  int task = blockIdx.y;
  if (task == 0) {
    float u0 = U[i*4+0], u1 = U[i*4+1], u2 = U[i*4+2], u3 = U[i*4+3];
    for (int j = threadIdx.x; j < Hn; j += 256) {
      float a = u0*V[j*4+0] + u1*V[j*4+1] + u2*V[j*4+2] + u3*V[j*4+3]
              + S[i*Hn+j] - S[j*Hn+i];
      if (i == j) a += -(float)(i+1) / 768.0f;
      Af[i*Hn+j]  = a;
      AfT[j*Hn+i] = a;
      Abf[i*Hn+j] = f2bf(a);
    }
    if (i == 0) for (int j = threadIdx.x; j < 1024; j += 256) zp[j] = 0;
  } else {
    const float* src = (task==1) ? Bm : (task==2) ? Cm : gw;
    unsigned short* dst = (task==1) ? Bmb : (task==2) ? Cmb : gwb;
    for (int j = threadIdx.x; j < Hn; j += 256) dst[i*Hn+j] = f2bf(src[i*Hn+j]);
  }
}

// ---------------------------------------------------------------------------
// k_rms: one wave per row (row = b*2048 + t); write xn in (t,b) order, bf16.
__global__ __launch_bounds__(256) void k_rms(
    const float* __restrict__ x, const float* __restrict__ scale,
    unsigned short* __restrict__ xn) {
  int row  = blockIdx.x * 4 + (threadIdx.x >> 6);
  int lane = threadIdx.x & 63;
  int b = row >> 11, t = row & 2047;
  const float* xr = x + (long)row * Hn;
  float v[12];
  float ss = 0.f;
#pragma unroll
  for (int j = 0; j < 12; ++j) { v[j] = xr[lane + j*64]; ss += v[j]*v[j]; }
#pragma unroll
  for (int off = 1; off < 64; off <<= 1) ss += __shfl_xor(ss, off);
  float inv = 1.0f / sqrtf(ss / 768.0f + 1e-8f);
  unsigned short* dst = xn + ((long)t * 8 + b) * Hn;
#pragma unroll
  for (int j = 0; j < 12; ++j) dst[lane + j*64] = f2bf(v[j] * inv * scale[lane + j*64]);
}

// ---------------------------------------------------------------------------
// k_sq: Z = X @ X, hi/lo bf16 (3 passes). Writes Z rm + Z^T rm f32 + bf16.
// 64x64 tile, 256 thr (4 waves 2x2), grid (12,12) = 144 blocks.
__global__ __launch_bounds__(256) void k_sq(
    const float* __restrict__ X, const float* __restrict__ XT,
    float* __restrict__ Z, float* __restrict__ ZT,
    unsigned short* __restrict__ Zbf) {
  int tid = threadIdx.x, lane = tid & 63, w = tid >> 6;
  int mw = w >> 1, nw = w & 1, l15 = lane & 15, lhi = lane >> 4;
  int rb = blockIdx.x * 64, cb = blockIdx.y * 64;
  ffrag acc[2][2] = {};
  for (int kt = 0; kt < 24; ++kt) {
    int k0 = kt*32 + lhi*8;
    BF8 ah[2], al[2], bh[2], bl[2];
#pragma unroll
    for (int mt = 0; mt < 2; ++mt) {
      const f4* p = (const f4*)(X + (long)(rb + mw*32 + mt*16 + l15) * Hn + k0);
      f4 x0 = p[0], x1 = p[1];
#pragma unroll
      for (int j = 0; j < 8; ++j) {
        float f = (j < 4) ? x0[j] : x1[j-4];
        unsigned short h = f2bf(f);
        ah[mt].u[j] = h; al[mt].u[j] = f2bf(f - bf2f(h));
      }
    }
#pragma unroll
    for (int nt = 0; nt < 2; ++nt) {
      const f4* p = (const f4*)(XT + (long)(cb + nw*32 + nt*16 + l15) * Hn + k0);
      f4 x0 = p[0], x1 = p[1];
#pragma unroll
      for (int j = 0; j < 8; ++j) {
        float f = (j < 4) ? x0[j] : x1[j-4];
        unsigned short h = f2bf(f);
        bh[nt].u[j] = h; bl[nt].u[j] = f2bf(f - bf2f(h));
      }
    }
#pragma unroll
    for (int mt = 0; mt < 2; ++mt)
#pragma unroll
      for (int nt = 0; nt < 2; ++nt) {
        acc[mt][nt] = mfma16(ah[mt].v, bh[nt].v, acc[mt][nt]);
        acc[mt][nt] = mfma16(ah[mt].v, bl[nt].v, acc[mt][nt]);
        acc[mt][nt] = mfma16(al[mt].v, bh[nt].v, acc[mt][nt]);
      }
  }
#pragma unroll
  for (int mt = 0; mt < 2; ++mt)
#pragma unroll
    for (int nt = 0; nt < 2; ++nt)
#pragma unroll
      for (int q = 0; q < 4; ++q) {
        int grow = rb + mw*32 + mt*16 + lhi*4 + q;
        int gcol = cb + nw*32 + nt*16 + l15;
        float vv = acc[mt][nt][q];
        Z[(long)grow*Hn + gcol] = vv;
        ZT[(long)gcol*Hn + grow] = vv;
        Zbf[(long)grow*Hn + gcol] = f2bf(vv);
      }
}

// ---------------------------------------------------------------------------
// k_lvl<MODE>: 128x256 block tile, BK=32, 24 K-steps, 512 thr (8 waves 2x4,
// wave tile 64x64). 2-buf LDS, stage-early, ONE __syncthreads per step.
// MODE 0 (u):      out = A0 @ B0^T, dup-write both halves.        grid 384
// MODE 1 (level):  out = res + A0[r -/+ sh] @ B0^T.               grid 768
// MODE 2 (combine):out = res[r]+res[r+16384]
//                        + (A0[r-sh]+A0[r+16384+sh]) @ B0^T.      grid 384
template<int MODE>
__global__ __launch_bounds__(512) void k_lvl(
    const unsigned short* __restrict__ A0s, const unsigned short* __restrict__ B0s,
    const unsigned short* __restrict__ res, unsigned short* __restrict__ outb,
    const unsigned short* __restrict__ zp, int sh) {
  constexpr int NS   = (MODE == 2) ? 2 : 1;        // A streams
  constexpr int BUFS = NS * 4096 + 8192;           // shorts per buffer
  __shared__ __align__(16) unsigned short ldsb[2 * BUFS];

  const int tid = threadIdx.x, lane = tid & 63, w = tid >> 6;
  const int l15 = lane & 15, lhi = lane >> 4;
  const int wr = w >> 2, wc = w & 3;               // 2 x 4 wave grid

  // XCD-aware bijective block swizzle (m204), col-fast decompose (ncol=3).
  const int nwg = gridDim.x;
  const int q8 = nwg >> 3, r8 = nwg & 7, xcd = blockIdx.x & 7, fo = blockIdx.x >> 3;
  const int wg = (xcd < r8 ? xcd*(q8+1) : r8*(q8+1) + (xcd - r8)*q8) + fo;
  const int cb = wg % 3, rbk = wg / 3;
  const long r0  = (long)rbk * 128;
  const long bc0 = (long)cb * 256;
  const int dir = (MODE == 1 && r0 >= 16384) ? 1 : 0;

  bool skip = false;
  if (MODE == 1)
    skip = dir ? (r0 >= 32768 - sh) : (r0 + 128 <= sh);

  // staging: A tile is 128x32 (8KB) = 1 glds16/thread; B tile 256x32 = 2.
  const int rowin = lane >> 2, ch = lane & 3;
  const int rA = w*16 + rowin;
  const int cswz = ch ^ ((rowin ^ (rowin >> 2)) & 3);  // row%16 = rowin
  long gA[NS]; bool vA[NS];
#pragma unroll
  for (int s = 0; s < NS; ++s) {
    long gr; bool ok = true;
    if (MODE == 0) {
      gr = r0 + rA;
    } else if (MODE == 1) {
      gr = r0 + rA + (dir ? sh : -sh);
      ok = dir ? (gr < 32768) : (gr >= 0);
    } else {
      if (s == 0) { gr = r0 + rA - sh;         ok = (gr >= 0);    }
      else        { gr = r0 + rA + 16384 + sh; ok = (gr < 32768); }
    }
    vA[s] = ok; gA[s] = gr * Hn + cswz*8;
  }
  long gB[2];
#pragma unroll
  for (int j = 0; j < 2; ++j)
    gB[j] = (bc0 + j*128 + rA) * Hn + cswz*8;

  auto stage = [&](int buf, int kt) {
    const int ko = kt * 32;
    unsigned short* dst = ldsb + buf * BUFS;
#pragma unroll
    for (int s = 0; s < NS; ++s) {
      const unsigned short* g = vA[s] ? (A0s + gA[s] + ko) : zp;
      glds16(g, dst + s*4096 + w*512);
    }
#pragma unroll
    for (int j = 0; j < 2; ++j)
      glds16(B0s + gB[j] + ko, dst + NS*4096 + j*4096 + w*512);
  };

  ffrag acc[4][4] = {};
  const int cx = (lhi ^ ((l15 ^ (l15 >> 2)) & 3)) * 8;   // swizzled read chunk

  if (!skip) {
    stage(0, 0);
    __syncthreads();
    int cur = 0;
    for (int kt = 0; kt < 24; ++kt) {
      if (kt < 23) stage(cur ^ 1, kt + 1);   // issue next tile BEFORE compute
      const unsigned short* L = ldsb + cur * BUFS;
      bfrag a[NS][4], b[4];
#pragma unroll
      for (int mt = 0; mt < 4; ++mt) {
        const int row = wr*64 + mt*16 + l15;
#pragma unroll
        for (int s = 0; s < NS; ++s)
          a[s][mt] = *(const bfrag*)&L[s*4096 + row*32 + cx];
      }
#pragma unroll
      for (int nt = 0; nt < 4; ++nt) {
        const int row = wc*64 + nt*16 + l15;
        b[nt] = *(const bfrag*)&L[NS*4096 + row*32 + cx];
      }
#pragma unroll
      for (int mt = 0; mt < 4; ++mt)
#pragma unroll
        for (int nt = 0; nt < 4; ++nt) {
          acc[mt][nt] = mfma16(a[0][mt], b[nt], acc[mt][nt]);
          if (NS == 2) acc[mt][nt] = mfma16(a[1][mt], b[nt], acc[mt][nt]);
        }
      __syncthreads();                       // staged tile ready; reads done
      cur ^= 1;
    }
  }

  // ---- epilogue: 4 phases; phase p bounces acc[p] (32 rows x 256 f32) ----
  float* fl = (float*)ldsb;                  // 32 x BLS f32 = 33280 B
#pragma unroll
  for (int p = 0; p < 4; ++p) {
    __syncthreads();
#pragma unroll
    for (int nt = 0; nt < 4; ++nt)
#pragma unroll
      for (int q = 0; q < 4; ++q)
        fl[(wr*16 + lhi*4 + q)*BLS + wc*64 + nt*16 + l15] = acc[p][nt][q];
    __syncthreads();
    for (int i = tid; i < 2048; i += 512) {
      const int srow = i >> 6;               // 0..31
      const int cc   = (i & 63) << 2;        // 0..252
      f4 v = *(const f4*)&fl[srow*BLS + cc];
      const long grow = r0 + (srow >> 4)*64 + p*16 + (srow & 15);
      const long gcol = bc0 + cc;
      const long go = grow * Hn + gcol;
      if (MODE == 0) {
        s4v ov;
#pragma unroll
        for (int j = 0; j < 4; ++j) ((unsigned short*)&ov)[j] = f2bf(v[j]);
        *(s4v*)&outb[go] = ov;
        *(s4v*)&outb[go + (long)16384*Hn] = ov;
      } else if (MODE == 1) {
        s4v rv = *(const s4v*)&res[go];
#pragma unroll
        for (int j = 0; j < 4; ++j) v[j] += bf2f(((unsigned short*)&rv)[j]);
        s4v ov;
#pragma unroll
        for (int j = 0; j < 4; ++j) ((unsigned short*)&ov)[j] = f2bf(v[j]);
        *(s4v*)&outb[go] = ov;
      } else {
        s4v ra = *(const s4v*)&res[go];
        s4v rb2 = *(const s4v*)&res[go + (long)16384*Hn];
#pragma unroll
        for (int j = 0; j < 4; ++j)
          v[j] += bf2f(((unsigned short*)&ra)[j]) + bf2f(((unsigned short*)&rb2)[j]);
        s4v ov;
#pragma unroll
        for (int j = 0; j < 4; ++j) ((unsigned short*)&ov)[j] = f2bf(v[j]);
        *(s4v*)&outb[go] = ov;
      }
    }
  }
}

// ---------------------------------------------------------------------------
// k_fin: fused final. 128x128 tile, BK=32, 256 thr (4 waves 2x2, wave 64x64).
// 2-buf, vmcnt(0)+barrier+stage(kt+1).
// outf = x + alpha*0.5*(A0@B0^T) * sigmoid(A1@B1^T + gb)   (row = t*8+b)
__global__ __launch_bounds__(256) void k_fin(
    const unsigned short* __restrict__ A0s, const unsigned short* __restrict__ A1s,
    const unsigned short* __restrict__ B0s, const unsigned short* __restrict__ B1s,
    const unsigned short* __restrict__ zp,
    const float* __restrict__ gb, const float* __restrict__ alpha,
    const float* __restrict__ x, float* __restrict__ outf) {
  __shared__ __align__(16) char smem[2 * 4 * 8192];
  unsigned short* ldsb = (unsigned short*)smem;

  const int tid = threadIdx.x, lane = tid & 63, w = tid >> 6;
  const int l15 = lane & 15, lhi = lane >> 4;
  const int wr = w >> 1, wc = w & 1;

  const int nwg = gridDim.x;
  const int q8 = nwg >> 3, r8 = nwg & 7, xcd = blockIdx.x & 7, fo = blockIdx.x >> 3;
  const int wg = (xcd < r8 ? xcd*(q8+1) : r8*(q8+1) + (xcd - r8)*q8) + fo;
  const int cb = wg % 6, rbk = wg / 6;
  const long r0 = (long)rbk * 128;
  const long bc0 = (long)cb * 128;

  const int rowin = lane >> 2, ch = lane & 3;
  long gA[2][2]; long gB[2][2]; int lbase[2];
#pragma unroll
  for (int jj = 0; jj < 2; ++jj) {
    const int inst = w*2 + jj;
    const int r = inst*16 + rowin;
    const int c = ch ^ ((r ^ (r >> 2)) & 3);
    lbase[jj] = inst * 512;
    gA[0][jj] = (r0 + r) * Hn + c*8;
    gA[1][jj] = gA[0][jj];
    gB[0][jj] = (bc0 + r) * Hn + c*8;
    gB[1][jj] = gB[0][jj];
  }

  auto stage = [&](int buf, int kt) {
    const int ko = kt * 32;
    unsigned short* dst = ldsb + buf * 16384;
#pragma unroll
    for (int jj = 0; jj < 2; ++jj) {
      glds16(A0s + gA[0][jj] + ko, dst + 0*4096 + lbase[jj]);
      glds16(A1s + gA[1][jj] + ko, dst + 1*4096 + lbase[jj]);
      glds16(B0s + gB[0][jj] + ko, dst + 2*4096 + lbase[jj]);
      glds16(B1s + gB[1][jj] + ko, dst + 3*4096 + lbase[jj]);
    }
  };

  ffrag acc[4][4] = {};
  ffrag accZ[4][4] = {};
  const int cx = (lhi ^ ((l15 ^ (l15 >> 2)) & 3)) * 8;

  stage(0, 0);
  int cur = 0;
  for (int kt = 0; kt < 24; ++kt) {
    asm volatile("s_waitcnt vmcnt(0)" ::: "memory");
    __builtin_amdgcn_s_barrier();
    if (kt < 23) stage(cur ^ 1, kt + 1);
    const unsigned short* L = ldsb + cur * 16384;
    bfrag a[2][4], b0[4], b1[4];
#pragma unroll
    for (int mt = 0; mt < 4; ++mt) {
      const int row = wr*64 + mt*16 + l15;
      a[0][mt] = *(const bfrag*)&L[row*32 + cx];
      a[1][mt] = *(const bfrag*)&L[4096 + row*32 + cx];
    }
#pragma unroll
    for (int nt = 0; nt < 4; ++nt) {
      const int row = wc*64 + nt*16 + l15;
      b0[nt] = *(const bfrag*)&L[2*4096 + row*32 + cx];
      b1[nt] = *(const bfrag*)&L[3*4096 + row*32 + cx];
    }
#pragma unroll
    for (int mt = 0; mt < 4; ++mt)
#pragma unroll
      for (int nt = 0; nt < 4; ++nt) {
        acc[mt][nt]  = mfma16(a[0][mt], b0[nt], acc[mt][nt]);
        accZ[mt][nt] = mfma16(a[1][mt], b1[nt], accZ[mt][nt]);
      }
    cur ^= 1;
  }

  // gate in fragment layout
  const float al = alpha[0];
  float gvals[4];
#pragma unroll
  for (int nt = 0; nt < 4; ++nt) gvals[nt] = gb[bc0 + wc*64 + nt*16 + l15];
#pragma unroll
  for (int mt = 0; mt < 4; ++mt)
#pragma unroll
    for (int nt = 0; nt < 4; ++nt)
#pragma unroll
      for (int q = 0; q < 4; ++q) {
        float z = accZ[mt][nt][q] + gvals[nt];
        float g = 1.0f / (1.0f + __expf(-z));
        acc[mt][nt][q] *= al * 0.5f * g;
      }

  float* fl = (float*)smem;                 // 64 x FLS f32
#pragma unroll
  for (int hh = 0; hh < 2; ++hh) {
    __syncthreads();
    if (wr == hh) {
#pragma unroll
      for (int mt = 0; mt < 4; ++mt)
#pragma unroll
        for (int nt = 0; nt < 4; ++nt)
#pragma unroll
          for (int q = 0; q < 4; ++q)
            fl[(mt*16 + lhi*4 + q)*FLS + wc*64 + nt*16 + l15] = acc[mt][nt][q];
    }
    __syncthreads();
    for (int i = tid; i < 2048; i += 256) {
      const int row = i >> 5;
      const int cc  = (i & 31) << 2;
      f4 v = *(const f4*)&fl[row*FLS + cc];
      const long grow = r0 + hh*64 + row;
      const long gcol = bc0 + cc;
      const long t = grow >> 3, b = grow & 7;
      const long o = (b*2048 + t)*Hn + gcol;
      f4 xv = *(const f4*)&x[o];
      f4 ov;
#pragma unroll
      for (int j = 0; j < 4; ++j) ov[j] = xv[j] + v[j];
      *(f4*)&outf[o] = ov;
    }
  }
}

// ---------------------------------------------------------------------------
extern "C" void kernel_launch(void* const* d_in, const int* in_sizes, int n_in,
                              void* d_out, int out_size, void* d_ws, size_t ws_size,
                              hipStream_t stream) {
  const float* x     = (const float*)d_in[0];
  const float* scale = (const float*)d_in[1];
  const float* U     = (const float*)d_in[2];
  const float* V     = (const float*)d_in[3];
  const float* S     = (const float*)d_in[4];
  const float* Bm    = (const float*)d_in[5];
  const float* Cm    = (const float*)d_in[6];
  const float* gw    = (const float*)d_in[7];
  const float* gb    = (const float*)d_in[8];
  const float* alpha = (const float*)d_in[9];
  float* out = (float*)d_out;

  char* p = (char*)d_ws;
  auto alloc = [&](size_t sz) { char* r = p; p += (sz + 255) & ~(size_t)255; return r; };

  const size_t SZ_X  = (size_t)32768 * Hn * sizeof(unsigned short);  // 50.3MB
  const size_t SZ_BF = (size_t)16384 * Hn * sizeof(unsigned short);  // 25.2MB
  const size_t SZ_M  = (size_t)Hn * Hn * sizeof(float);              // 2.36MB
  const size_t SZ_MB = (size_t)Hn * Hn * sizeof(unsigned short);     // 1.18MB

  unsigned short* xn = (unsigned short*)alloc(SZ_BF);
  unsigned short* XA = (unsigned short*)alloc(SZ_X);
  unsigned short* XB = (unsigned short*)alloc(SZ_X);
  float* Af  = (float*)alloc(SZ_M);
  float* AfT = (float*)alloc(SZ_M);
  float* P1  = (float*)alloc(SZ_M);
  float* P1T = (float*)alloc(SZ_M);
  float* P2  = (float*)alloc(SZ_M);
  float* P2T = (float*)alloc(SZ_M);
  unsigned short* Abf = (unsigned short*)alloc(SZ_MB);
  unsigned short* Ab[10];                      // A^2..A^1024 bf16
  for (int i = 0; i < 10; ++i) Ab[i] = (unsigned short*)alloc(SZ_MB);
  unsigned short* Bmb = (unsigned short*)alloc(SZ_MB);
  unsigned short* Cmb = (unsigned short*)alloc(SZ_MB);
  unsigned short* gwb = (unsigned short*)alloc(SZ_MB);
  unsigned short* zp  = (unsigned short*)alloc(1024 * sizeof(unsigned short));

  if ((size_t)(p - (char*)d_ws) > ws_size) return;  // workspace too small

  k_abuild<<<dim3(768, 4), 256, 0, stream>>>(U, V, S, Bm, Cm, gw,
      Af, AfT, Abf, Bmb, Cmb, gwb, zp);
  k_rms<<<4096, 256, 0, stream>>>(x, scale, xn);

  // squaring chain: A -> A^2 -> ... -> A^1024 (bf16 emitted each step)
  const float* sx = Af; const float* sxt = AfT;
  float* za = P1; float* zat = P1T; float* zb = P2; float* zbt = P2T;
  for (int i = 0; i < 10; ++i) {
    k_sq<<<dim3(12, 12), 256, 0, stream>>>(sx, sxt, za, zat, Ab[i]);
    sx = za; sxt = zat;
    float* t1 = za; float* t2 = zat; za = zb; zat = zbt; zb = t1; zbt = t2;
  }

  // u = xn@Bm^T, duplicated into fwd+bwd halves of XA   (X_1)
  k_lvl<0><<<384, 512, 0, stream>>>(xn, Bmb, nullptr, XA, zp, 0);

  // doubling levels k=1..512 (shift sh=8k rows)
  unsigned short* src = XA; unsigned short* dst = XB;
  for (int i = 0; i < 10; ++i) {
    const unsigned short* W = (i == 0) ? Abf : Ab[i-1];
    k_lvl<1><<<768, 512, 0, stream>>>(src, W, src, dst, zp, 8 << i);
    unsigned short* t = src; src = dst; dst = t;
  }
  // src = XA holds X_1024 (both dirs). Combine (k=1024) + fwd/bwd sum -> XB:
  k_lvl<2><<<384, 512, 0, stream>>>(src, Ab[9], src, XB, zp, 8192);

  // out = x + alpha*0.5*(Xsum@Cm^T)*sigmoid(xn@gw^T+gb)
  k_fin<<<768, 256, 0, stream>>>(XB, xn, Cmb, gwb, zp, gb, alpha, x, out);
}